// Round 1
// baseline (183.566 us; speedup 1.0000x reference)
//
#include <hip/hip_runtime.h>

#define HH 192
#define WW 192
#define HW 36864          // 192*192
#define BB 64
#define NPIX 2359296      // 64*192*192

// ---------------- conv helpers ----------------
__device__ __forceinline__ float conv3x3(const float* __restrict__ img, int y, int x,
                                         const float* __restrict__ w9) {
  float s = 0.f;
#pragma unroll
  for (int di = 0; di < 3; ++di) {
    int yy = y + di - 1;
    if (yy < 0 || yy >= HH) continue;
    const float* row = img + yy * WW;
#pragma unroll
    for (int dj = 0; dj < 3; ++dj) {
      int xx = x + dj - 1;
      if (xx < 0 || xx >= WW) continue;
      s += row[xx] * w9[di * 3 + dj];
    }
  }
  return s;
}

// h = relu(conv3x3(grid, hp_w) + hp_b)
__global__ __launch_bounds__(256) void k_conv1(const float* __restrict__ X,
                                               const float* __restrict__ w9,
                                               const float* __restrict__ b1,
                                               float* __restrict__ h) {
  int idx = blockIdx.x * 256 + threadIdx.x;
  if (idx >= NPIX) return;
  int b = idx / HW;
  int rem = idx - b * HW;
  int y = rem / WW;
  int x = rem - y * WW;
  const float* g = X + (size_t)b * (2 * HW);  // channel 0
  float s = conv3x3(g, y, x, w9) + b1[0];
  h[idx] = s > 0.f ? s : 0.f;
}

// p = sigmoid(conv3x3(h, p_w) + p_b);  v0 = goal - 1
__global__ __launch_bounds__(256) void k_conv2(const float* __restrict__ X,
                                               const float* __restrict__ w9,
                                               const float* __restrict__ b1,
                                               const float* __restrict__ h,
                                               float* __restrict__ p_out,
                                               float* __restrict__ v0) {
  int idx = blockIdx.x * 256 + threadIdx.x;
  if (idx >= NPIX) return;
  int b = idx / HW;
  int rem = idx - b * HW;
  int y = rem / WW;
  int x = rem - y * WW;
  float z = conv3x3(h + (size_t)b * HW, y, x, w9) + b1[0];
  float p = 1.f / (1.f + __expf(-z));
  float goal = X[(size_t)b * (2 * HW) + HW + rem];
  p_out[idx] = p;
  v0[idx] = goal - 1.f;
}

// ---------------- phase kernel: 7 value-iteration steps in LDS ----------------
#define NCH 48        // 192 / 4 float4 chunks per row
#define WR 64         // window rows held in LDS
#define LDST 196      // padded row stride (floats)
#define TPB 768       // 48 chunks x 16 row-groups
#define RPT 4         // rows per thread
#define PHASE_ITERS 7

__global__ __launch_bounds__(TPB) void k_phase(const float* __restrict__ v_in,
                                               float* __restrict__ v_out,
                                               const float* __restrict__ p_glob,
                                               const float* __restrict__ X) {
  __shared__ __align__(16) float vs[WR * LDST];

  int blk = blockIdx.x;
  int b = blk >> 2;
  int s = blk & 3;
  // window start row (halo 8, clamped): {0, 40, 88, 128}
  int ys = (s == 0) ? 0 : (s == 1) ? 40 : (s == 2) ? 88 : 128;
  int y0o = s * 48;                 // first output row (global)
  int roff = y0o - ys;              // first output row (LDS): {0,8,8,16}

  int tid = threadIdx.x;
  const float* vin_img = v_in + (size_t)b * HW;

  // ---- load 64-row window into LDS ----
  for (int t = tid; t < WR * NCH; t += TPB) {
    int r = t / NCH, c2 = t - r * NCH;
    float4 val = *reinterpret_cast<const float4*>(vin_img + (ys + r) * WW + c2 * 4);
    *reinterpret_cast<float4*>(&vs[r * LDST + c2 * 4]) = val;
  }

  // ---- pinned per-thread p, c registers ----
  int ch = tid % NCH;
  int g = tid / NCH;  // 0..15
  int yb = g * RPT;   // base row in window
  int ch4 = ch * 4;

  float4 pr[RPT], cr[RPT];
  {
    const float* pimg = p_glob + (size_t)b * HW;
    const float* gimg = X + (size_t)b * (2 * HW) + HW;
#pragma unroll
    for (int i = 0; i < RPT; ++i) {
      int off = (ys + yb + i) * WW + ch4;
      float4 p4 = *reinterpret_cast<const float4*>(pimg + off);
      float4 g4 = *reinterpret_cast<const float4*>(gimg + off);
      pr[i] = p4;
      cr[i].x = (g4.x - 1.f) * (1.f - p4.x);
      cr[i].y = (g4.y - 1.f) * (1.f - p4.y);
      cr[i].z = (g4.z - 1.f) * (1.f - p4.z);
      cr[i].w = (g4.w - 1.f) * (1.f - p4.w);
    }
  }
  __syncthreads();

  int ilw0 = (ch > 0) ? (ch4 - 1) : 0;  // left scalar offset within row (clamped idx; value overridden at ch==0)
  int irx0 = ch4 + 4;                   // right scalar (row pad keeps it in-bounds at ch==47; overridden)

#pragma unroll 1
  for (int it = 0; it < PHASE_ITERS; ++it) {
    float4 nv[RPT];
    int ym1 = (yb > 0) ? (yb - 1) : 0;
    float4 o_prev = *reinterpret_cast<const float4*>(&vs[ym1 * LDST + ch4]);
    float4 o_cur = *reinterpret_cast<const float4*>(&vs[yb * LDST + ch4]);
    float lw_prev = vs[ym1 * LDST + ilw0];
    float lw_cur = vs[yb * LDST + ilw0];
    float rx_prev = vs[ym1 * LDST + irx0];
    float rx_cur = vs[yb * LDST + irx0];

#pragma unroll
    for (int i = 0; i < RPT; ++i) {
      int y = yb + i;
      int yp1 = (y == WR - 1) ? y : (y + 1);
      float4 o_next = *reinterpret_cast<const float4*>(&vs[yp1 * LDST + ch4]);
      float lw_next = vs[yp1 * LDST + ilw0];
      float rx_next = vs[yp1 * LDST + irx0];

      float4 vm;
      vm.x = fmaxf(fmaxf(o_prev.x, o_cur.x), o_next.x);
      vm.y = fmaxf(fmaxf(o_prev.y, o_cur.y), o_next.y);
      vm.z = fmaxf(fmaxf(o_prev.z, o_cur.z), o_next.z);
      vm.w = fmaxf(fmaxf(o_prev.w, o_cur.w), o_next.w);
      float lwm = fmaxf(fmaxf(lw_prev, lw_cur), lw_next);
      float rxm = fmaxf(fmaxf(rx_prev, rx_cur), rx_next);
      if (ch == 0) lwm = vm.x;          // clamp at true left image edge
      if (ch == NCH - 1) rxm = vm.w;    // clamp at true right image edge

      float4 hm;
      hm.x = fmaxf(lwm, fmaxf(vm.x, vm.y));
      hm.y = fmaxf(vm.x, fmaxf(vm.y, vm.z));
      hm.z = fmaxf(vm.y, fmaxf(vm.z, vm.w));
      hm.w = fmaxf(vm.z, fmaxf(vm.w, rxm));

      nv[i].x = fmaxf(o_cur.x, fmaf(pr[i].x, hm.x, cr[i].x));
      nv[i].y = fmaxf(o_cur.y, fmaf(pr[i].y, hm.y, cr[i].y));
      nv[i].z = fmaxf(o_cur.z, fmaf(pr[i].z, hm.z, cr[i].z));
      nv[i].w = fmaxf(o_cur.w, fmaf(pr[i].w, hm.w, cr[i].w));

      o_prev = o_cur; o_cur = o_next;
      lw_prev = lw_cur; lw_cur = lw_next;
      rx_prev = rx_cur; rx_cur = rx_next;
    }
    __syncthreads();
#pragma unroll
    for (int i = 0; i < RPT; ++i)
      *reinterpret_cast<float4*>(&vs[(yb + i) * LDST + ch4]) = nv[i];
    __syncthreads();
  }

  // ---- store the 48 clean output rows ----
  float* vout_img = v_out + (size_t)b * HW;
  for (int t = tid; t < 48 * NCH; t += TPB) {
    int r = t / NCH, c2 = t - r * NCH;
    float4 val = *reinterpret_cast<const float4*>(&vs[(roff + r) * LDST + c2 * 4]);
    *reinterpret_cast<float4*>(vout_img + (y0o + r) * WW + c2 * 4) = val;
  }
}

// ---------------- launch ----------------
extern "C" void kernel_launch(void* const* d_in, const int* in_sizes, int n_in,
                              void* d_out, int out_size, void* d_ws, size_t ws_size,
                              hipStream_t stream) {
  const float* X = (const float*)d_in[0];
  const float* hp_w = (const float*)d_in[1];
  const float* hp_b = (const float*)d_in[2];
  const float* p_w = (const float*)d_in[3];
  const float* p_b = (const float*)d_in[4];

  float* out = (float*)d_out;
  float* out_v = out;          // NPIX floats
  float* out_p = out + NPIX;   // NPIX floats
  float* vA = (float*)d_ws;    // NPIX floats of scratch

  // h temporarily lives in out_v (consumed by conv2 before any phase writes there)
  float* h = out_v;

  int nblk = (NPIX + 255) / 256;
  k_conv1<<<nblk, 256, 0, stream>>>(X, hp_w, hp_b, h);
  k_conv2<<<nblk, 256, 0, stream>>>(X, p_w, p_b, h, out_p, vA);

  // 5 phases x 7 iters = 35; ping-pong vA <-> out_v, final lands in out_v
  k_phase<<<BB * 4, TPB, 0, stream>>>(vA, out_v, out_p, X);
  k_phase<<<BB * 4, TPB, 0, stream>>>(out_v, vA, out_p, X);
  k_phase<<<BB * 4, TPB, 0, stream>>>(vA, out_v, out_p, X);
  k_phase<<<BB * 4, TPB, 0, stream>>>(out_v, vA, out_p, X);
  k_phase<<<BB * 4, TPB, 0, stream>>>(vA, out_v, out_p, X);
}